// Round 1
// baseline (306.628 us; speedup 1.0000x reference)
//
#include <hip/hip_runtime.h>
#include <math.h>

#define NN 50000
#define NE 800000
#define CD 128

// ---------------- CSR build ----------------

__global__ void count_k(const int* __restrict__ ei, int* __restrict__ counts) {
    int e = blockIdx.x * 256 + threadIdx.x;
    if (e < NE) atomicAdd(&counts[ei[NE + e]], 1);
}

__global__ void blocksum_k(const int* __restrict__ counts, int* __restrict__ bsum) {
    __shared__ int s[256];
    int t = threadIdx.x;
    int n = blockIdx.x * 256 + t;
    s[t] = (n < NN) ? counts[n] : 0;
    __syncthreads();
    for (int off = 128; off > 0; off >>= 1) {
        if (t < off) s[t] += s[t + off];
        __syncthreads();
    }
    if (t == 0) bsum[blockIdx.x] = s[0];
}

__global__ void scan_bsum_k(int* __restrict__ bsum, int nb) {
    __shared__ int s[256];
    int t = threadIdx.x;
    int v = (t < nb) ? bsum[t] : 0;
    s[t] = v;
    __syncthreads();
    for (int off = 1; off < 256; off <<= 1) {
        int add = (t >= off) ? s[t - off] : 0;
        __syncthreads();
        s[t] += add;
        __syncthreads();
    }
    if (t < nb) bsum[t] = s[t] - v;   // exclusive scan
}

__global__ void offsets_k(const int* __restrict__ counts, const int* __restrict__ bsum,
                          int* __restrict__ offsets, int* __restrict__ cursor) {
    __shared__ int s[256];
    int t = threadIdx.x;
    int n = blockIdx.x * 256 + t;
    int v = (n < NN) ? counts[n] : 0;
    s[t] = v;
    __syncthreads();
    for (int off = 1; off < 256; off <<= 1) {
        int add = (t >= off) ? s[t - off] : 0;
        __syncthreads();
        s[t] += add;
        __syncthreads();
    }
    int o = bsum[blockIdx.x] + s[t] - v;   // global exclusive prefix
    if (n < NN) { offsets[n] = o; cursor[n] = o; }
    if (n == NN - 1) offsets[NN] = o + v;  // == NE
}

__global__ void scatter_k(const int* __restrict__ ei, int* __restrict__ cursor,
                          int* __restrict__ csr) {
    int e = blockIdx.x * 256 + threadIdx.x;
    if (e < NE) {
        int dst = ei[NE + e];
        int pos = atomicAdd(&cursor[dst], 1);
        csr[pos] = ei[e];   // src
    }
}

// ---------------- per-node segment max ----------------
// One wave (64 lanes) per node; each lane owns 2 channels (float2).
// maxdiff[n] = (max over incoming src of x[src]) - x[n], or 0 if no edges.

__global__ void gather_k(const float* __restrict__ x, const int* __restrict__ offsets,
                         const int* __restrict__ csr, float* __restrict__ maxdiff) {
    int gid = blockIdx.x * 256 + threadIdx.x;
    int node = gid >> 6;
    int lane = gid & 63;
    if (node >= NN) return;
    int beg = offsets[node];
    int end = offsets[node + 1];
    const float2* x2 = (const float2*)x;
    float2 m = make_float2(-INFINITY, -INFINITY);
    for (int i = beg; i < end; i++) {
        int s = csr[i];
        float2 v = x2[(size_t)s * 64 + lane];
        m.x = fmaxf(m.x, v.x);
        m.y = fmaxf(m.y, v.y);
    }
    float2 r;
    if (end > beg) {
        float2 xd = x2[(size_t)node * 64 + lane];
        r.x = m.x - xd.x;
        r.y = m.y - xd.y;
    } else {
        r.x = 0.f;
        r.y = 0.f;
    }
    ((float2*)maxdiff)[(size_t)node * 64 + lane] = r;
}

// ---------------- fp32 GEMM: out = x @ W[0:128] + maxdiff @ W[128:256] + b ----------------
// 128 rows x 128 cols per 256-thread block, K staged in LDS chunks of 32,
// 8x8 micro-tile per thread. a_s stored transposed [k][row], rows padded to 132.

__global__ __launch_bounds__(256) void gemm_k(const float* __restrict__ x,
                                              const float* __restrict__ maxdiff,
                                              const float* __restrict__ W,
                                              const float* __restrict__ bias,
                                              float* __restrict__ out) {
    __shared__ float a_s[32][132];
    __shared__ float b_s[32][132];
    int t = threadIdx.x;
    int row0 = blockIdx.x * 128;
    int tx = t & 15;
    int ty = t >> 4;

    float acc[8][8];
#pragma unroll
    for (int i = 0; i < 8; i++)
#pragma unroll
        for (int j = 0; j < 8; j++) acc[i][j] = 0.f;

    for (int kt = 0; kt < 256; kt += 32) {
        const float* src = (kt < 128) ? (x + (size_t)row0 * 128 + kt)
                                      : (maxdiff + (size_t)row0 * 128 + (kt - 128));
        // A tile: 128 rows x 32 k, transposed into a_s[k][row]
#pragma unroll
        for (int i = 0; i < 4; i++) {
            int idx4 = t + i * 256;        // 0..1023 float4s
            int r = idx4 >> 3;             // row 0..127
            int k = (idx4 & 7) * 4;        // k 0..28
            float4 v = make_float4(0.f, 0.f, 0.f, 0.f);
            if (row0 + r < NN) v = *(const float4*)(src + (size_t)r * 128 + k);
            a_s[k + 0][r] = v.x;
            a_s[k + 1][r] = v.y;
            a_s[k + 2][r] = v.z;
            a_s[k + 3][r] = v.w;
        }
        // B tile: 32 k x 128 cols
#pragma unroll
        for (int i = 0; i < 4; i++) {
            int idx4 = t + i * 256;
            int k = idx4 >> 5;             // 0..31
            int c = (idx4 & 31) * 4;       // 0..124
            float4 v = *(const float4*)(W + (size_t)(kt + k) * 128 + c);
            *(float4*)&b_s[k][c] = v;
        }
        __syncthreads();

        for (int k = 0; k < 32; k++) {
            float a0[8], b0[8];
            *(float4*)&a0[0] = *(const float4*)&a_s[k][ty * 8];
            *(float4*)&a0[4] = *(const float4*)&a_s[k][ty * 8 + 4];
            *(float4*)&b0[0] = *(const float4*)&b_s[k][tx * 8];
            *(float4*)&b0[4] = *(const float4*)&b_s[k][tx * 8 + 4];
#pragma unroll
            for (int i = 0; i < 8; i++)
#pragma unroll
                for (int j = 0; j < 8; j++)
                    acc[i][j] = fmaf(a0[i], b0[j], acc[i][j]);
        }
        __syncthreads();
    }

#pragma unroll
    for (int i = 0; i < 8; i++) {
        int r = row0 + ty * 8 + i;
        if (r < NN) {
#pragma unroll
            for (int j = 0; j < 8; j += 4) {
                float4 v;
                v.x = acc[i][j + 0] + bias[tx * 8 + j + 0];
                v.y = acc[i][j + 1] + bias[tx * 8 + j + 1];
                v.z = acc[i][j + 2] + bias[tx * 8 + j + 2];
                v.w = acc[i][j + 3] + bias[tx * 8 + j + 3];
                *(float4*)(out + (size_t)r * 128 + tx * 8 + j) = v;
            }
        }
    }
}

// ---------------- launch ----------------

extern "C" void kernel_launch(void* const* d_in, const int* in_sizes, int n_in,
                              void* d_out, int out_size, void* d_ws, size_t ws_size,
                              hipStream_t stream) {
    const float* x = (const float*)d_in[0];
    const int* ei = (const int*)d_in[1];     // (2, E): [0..E)=src, [E..2E)=dst
    const float* W = (const float*)d_in[2];  // (256, 128) row-major
    const float* bias = (const float*)d_in[3];
    float* out = (float*)d_out;

    int* wsi = (int*)d_ws;
    int* counts  = wsi;                        // NN
    int* cursor  = wsi + 50048;                // NN
    int* offsets = wsi + 2 * 50048;            // NN+1
    int* bsum    = wsi + 3 * 50048;            // 256
    int* csr     = wsi + 3 * 50048 + 256;      // NE
    float* maxdiff = (float*)(wsi + 3 * 50048 + 256 + NE);  // NN*CD floats, 16B-aligned

    hipMemsetAsync(counts, 0, NN * sizeof(int), stream);

    int nb = (NN + 255) / 256;  // 196
    count_k<<<(NE + 255) / 256, 256, 0, stream>>>(ei, counts);
    blocksum_k<<<nb, 256, 0, stream>>>(counts, bsum);
    scan_bsum_k<<<1, 256, 0, stream>>>(bsum, nb);
    offsets_k<<<nb, 256, 0, stream>>>(counts, bsum, offsets, cursor);
    scatter_k<<<(NE + 255) / 256, 256, 0, stream>>>(ei, cursor, csr);
    gather_k<<<(NN * 64 + 255) / 256, 256, 0, stream>>>(x, offsets, csr, maxdiff);
    gemm_k<<<(NN + 127) / 128, 256, 0, stream>>>(x, maxdiff, W, bias, out);
}

// Round 3
// 245.557 us; speedup vs baseline: 1.2487x; 1.2487x over previous
//
#include <hip/hip_runtime.h>
#include <math.h>

#define NN 50000
#define NE 800000
#define CD 128

typedef __attribute__((ext_vector_type(8))) short short8;
typedef __attribute__((ext_vector_type(4))) float f32x4;

// ---------------- helpers ----------------

__device__ inline unsigned pack2bf(float lo, float hi) {
    unsigned a = __float_as_uint(lo), b = __float_as_uint(hi);
    a = (a + 0x7fffu + ((a >> 16) & 1u)) >> 16;
    b = (b + 0x7fffu + ((b >> 16) & 1u)) & 0xffff0000u;
    return a | b;
}

__device__ inline unsigned short f2bf(float f) {
    unsigned u = __float_as_uint(f);
    return (unsigned short)((u + 0x7fffu + ((u >> 16) & 1u)) >> 16);
}

// ---------------- CSR build ----------------

__global__ void count_k(const int* __restrict__ ei, int* __restrict__ counts) {
    int e = blockIdx.x * 256 + threadIdx.x;
    if (e < NE) atomicAdd(&counts[ei[NE + e]], 1);
}

__global__ void blocksum_k(const int* __restrict__ counts, int* __restrict__ bsum) {
    __shared__ int s[256];
    int t = threadIdx.x;
    int n = blockIdx.x * 256 + t;
    s[t] = (n < NN) ? counts[n] : 0;
    __syncthreads();
    for (int off = 128; off > 0; off >>= 1) {
        if (t < off) s[t] += s[t + off];
        __syncthreads();
    }
    if (t == 0) bsum[blockIdx.x] = s[0];
}

__global__ void scan_bsum_k(int* __restrict__ bsum, int nb) {
    __shared__ int s[256];
    int t = threadIdx.x;
    int v = (t < nb) ? bsum[t] : 0;
    s[t] = v;
    __syncthreads();
    for (int off = 1; off < 256; off <<= 1) {
        int add = (t >= off) ? s[t - off] : 0;
        __syncthreads();
        s[t] += add;
        __syncthreads();
    }
    if (t < nb) bsum[t] = s[t] - v;   // exclusive scan
}

__global__ void offsets_k(const int* __restrict__ counts, const int* __restrict__ bsum,
                          int* __restrict__ offsets, int* __restrict__ cursor) {
    __shared__ int s[256];
    int t = threadIdx.x;
    int n = blockIdx.x * 256 + t;
    int v = (n < NN) ? counts[n] : 0;
    s[t] = v;
    __syncthreads();
    for (int off = 1; off < 256; off <<= 1) {
        int add = (t >= off) ? s[t - off] : 0;
        __syncthreads();
        s[t] += add;
        __syncthreads();
    }
    int o = bsum[blockIdx.x] + s[t] - v;
    if (n < NN) { offsets[n] = o; cursor[n] = o; }
    if (n == NN - 1) offsets[NN] = o + v;
}

__global__ void scatter_k(const int* __restrict__ ei, int* __restrict__ cursor,
                          int* __restrict__ csr) {
    int e = blockIdx.x * 256 + threadIdx.x;
    if (e < NE) {
        int dst = ei[NE + e];
        int pos = atomicAdd(&cursor[dst], 1);
        csr[pos] = ei[e];
    }
}

// ---------------- cast: x -> bf16, W -> transposed bf16 Wt[n][k] ----------------
// NOTE: wt aliases the counts region — counts is dead after offsets_k, and
// cast_k runs after scatter_k in the per-call sequence.

__global__ void cast_k(const float* __restrict__ x, const float* __restrict__ W,
                       unsigned* __restrict__ xb, unsigned short* __restrict__ wt) {
    int tid = blockIdx.x * 256 + threadIdx.x;
    if (tid < NN * CD / 4) {                    // 1,600,000 float4s -> 3.2M uints
        float4 v = ((const float4*)x)[tid];
        uint2 r;
        r.x = pack2bf(v.x, v.y);
        r.y = pack2bf(v.z, v.w);
        ((uint2*)xb)[tid] = r;
    } else {
        int i = tid - NN * CD / 4;
        if (i < 2 * CD * CD) {                  // 32768 W elements
            int n = i >> 8, k = i & 255;
            wt[(size_t)n * 256 + k] = f2bf(W[(size_t)k * 128 + n]);
        }
    }
}

// ---------------- per-node segment max (bf16 in, bf16 out) ----------------
// One wave per node. Quarter q = lane>>4 handles edge e+q; c = lane&15 covers
// 8 channels (16B). Indices preloaded coalesced + distributed via shfl.

__global__ __launch_bounds__(256) void gather_k(const unsigned* __restrict__ xb,
                                                const int* __restrict__ offsets,
                                                const int* __restrict__ csr,
                                                unsigned* __restrict__ mdb) {
    int gid = blockIdx.x * 256 + threadIdx.x;
    int node = gid >> 6;
    if (node >= NN) return;
    int lane = threadIdx.x & 63;
    int q = lane >> 4;
    int c = lane & 15;
    int beg = offsets[node], end = offsets[node + 1];

    float m[8];
#pragma unroll
    for (int j = 0; j < 8; j++) m[j] = -INFINITY;

    for (int t0 = beg; t0 < end; t0 += 64) {
        int idxv = (t0 + lane < end) ? csr[t0 + lane] : -1;
        int nT = min(64, end - t0);
        for (int e = 0; e < nT; e += 4) {
            int s = __shfl(idxv, e + q);
            if (s >= 0) {
                uint4 v = *(const uint4*)(xb + (size_t)s * 64 + c * 4);
                m[0] = fmaxf(m[0], __uint_as_float(v.x << 16));
                m[1] = fmaxf(m[1], __uint_as_float(v.x & 0xffff0000u));
                m[2] = fmaxf(m[2], __uint_as_float(v.y << 16));
                m[3] = fmaxf(m[3], __uint_as_float(v.y & 0xffff0000u));
                m[4] = fmaxf(m[4], __uint_as_float(v.z << 16));
                m[5] = fmaxf(m[5], __uint_as_float(v.z & 0xffff0000u));
                m[6] = fmaxf(m[6], __uint_as_float(v.w << 16));
                m[7] = fmaxf(m[7], __uint_as_float(v.w & 0xffff0000u));
            }
        }
    }
#pragma unroll
    for (int j = 0; j < 8; j++) {
        m[j] = fmaxf(m[j], __shfl_xor(m[j], 16));
        m[j] = fmaxf(m[j], __shfl_xor(m[j], 32));
    }
    if (lane < 16) {
        uint4 r = make_uint4(0u, 0u, 0u, 0u);
        if (end > beg) {
            uint4 xd = *(const uint4*)(xb + (size_t)node * 64 + c * 4);
            float d0 = m[0] - __uint_as_float(xd.x << 16);
            float d1 = m[1] - __uint_as_float(xd.x & 0xffff0000u);
            float d2 = m[2] - __uint_as_float(xd.y << 16);
            float d3 = m[3] - __uint_as_float(xd.y & 0xffff0000u);
            float d4 = m[4] - __uint_as_float(xd.z << 16);
            float d5 = m[5] - __uint_as_float(xd.z & 0xffff0000u);
            float d6 = m[6] - __uint_as_float(xd.w << 16);
            float d7 = m[7] - __uint_as_float(xd.w & 0xffff0000u);
            r.x = pack2bf(d0, d1);
            r.y = pack2bf(d2, d3);
            r.z = pack2bf(d4, d5);
            r.w = pack2bf(d6, d7);
        }
        *(uint4*)(mdb + (size_t)node * 64 + c * 4) = r;
    }
}

// ---------------- bf16 MFMA GEMM: out = [xb | mdb] @ Wt^T + bias ----------------
// Block = 4 waves, 64 rows x 128 cols. Wave w: rows r0+w*16..+15, all 128 cols
// via 8 col-tiles of 16x16x32 MFMA. A-frags direct from global (16B/lane),
// B-frags from transposed Wt[n][k] (L1/L2-resident, 64 KB total).

__global__ __launch_bounds__(256) void gemm_k(const short* __restrict__ xb,
                                              const short* __restrict__ mdb,
                                              const short* __restrict__ wt,
                                              const float* __restrict__ bias,
                                              float* __restrict__ out) {
    int t = threadIdx.x;
    int w = t >> 6, lane = t & 63;
    int m = lane & 15, g = lane >> 4;
    int r0 = blockIdx.x * 64 + w * 16;
    int row = r0 + m;
    bool rowok = row < NN;

    f32x4 acc[8];
#pragma unroll
    for (int ct = 0; ct < 8; ct++) {
        float bv = bias[ct * 16 + m];
        acc[ct] = (f32x4){bv, bv, bv, bv};
    }

#pragma unroll
    for (int kc = 0; kc < 8; kc++) {
        int k0 = kc * 32;
        short8 a = (short8){0, 0, 0, 0, 0, 0, 0, 0};
        if (rowok) {
            const short* A = (kc < 4) ? (xb + (size_t)row * 128 + k0 + g * 8)
                                      : (mdb + (size_t)row * 128 + (k0 - 128) + g * 8);
            a = *(const short8*)A;
        }
#pragma unroll
        for (int ct = 0; ct < 8; ct++) {
            short8 b = *(const short8*)(wt + (size_t)(ct * 16 + m) * 256 + k0 + g * 8);
            acc[ct] = __builtin_amdgcn_mfma_f32_16x16x32_bf16(a, b, acc[ct], 0, 0, 0);
        }
    }

#pragma unroll
    for (int ct = 0; ct < 8; ct++) {
#pragma unroll
        for (int i = 0; i < 4; i++) {
            int rr = r0 + g * 4 + i;
            if (rr < NN) out[(size_t)rr * 128 + ct * 16 + m] = acc[ct][i];
        }
    }
}

// ---------------- launch ----------------

extern "C" void kernel_launch(void* const* d_in, const int* in_sizes, int n_in,
                              void* d_out, int out_size, void* d_ws, size_t ws_size,
                              hipStream_t stream) {
    const float* x = (const float*)d_in[0];
    const int* ei = (const int*)d_in[1];     // (2, E): [0..E)=src, [E..2E)=dst
    const float* W = (const float*)d_in[2];  // (256, 128) row-major
    const float* bias = (const float*)d_in[3];
    float* out = (float*)d_out;

    // Workspace layout (ints). Total = 7,350,400 ints = 29.40 MB (== round-1
    // proven footprint). wt ALIASES counts (counts dead before cast_k runs).
    int* wsi = (int*)d_ws;
    int* counts  = wsi;                          // 50048 ints (dead after offsets_k)
    int* cursor  = wsi + 50048;                  // 50048
    int* offsets = wsi + 100096;                 // 50048 (uses NN+1)
    int* bsum    = wsi + 150144;                 // 256
    int* csr     = wsi + 150400;                 // 800000
    unsigned* xb  = (unsigned*)(wsi + 950400);   // 3,200,000 uints (50000*128 bf16)
    unsigned* mdb = (unsigned*)(wsi + 4150400);  // 3,200,000 uints
    unsigned short* wt = (unsigned short*)wsi;   // 32768 bf16 = 16384 ints, aliases counts

    hipMemsetAsync(counts, 0, NN * sizeof(int), stream);

    int nb = (NN + 255) / 256;  // 196
    count_k<<<(NE + 255) / 256, 256, 0, stream>>>(ei, counts);
    blocksum_k<<<nb, 256, 0, stream>>>(counts, bsum);
    scan_bsum_k<<<1, 256, 0, stream>>>(bsum, nb);
    offsets_k<<<nb, 256, 0, stream>>>(counts, bsum, offsets, cursor);
    scatter_k<<<(NE + 255) / 256, 256, 0, stream>>>(ei, cursor, csr);
    cast_k<<<(NN * CD / 4 + 2 * CD * CD + 255) / 256, 256, 0, stream>>>(x, W, xb, wt);
    gather_k<<<(NN * 64 + 255) / 256, 256, 0, stream>>>(xb, offsets, csr, mdb);
    gemm_k<<<(NN + 63) / 64, 256, 0, stream>>>((const short*)xb, (const short*)mdb,
                                               (const short*)wt, bias, out);
}